// Round 2
// baseline (333.700 us; speedup 1.0000x reference)
//
#include <hip/hip_runtime.h>
#include <stdint.h>

// Round 2: 8-wave WG (4 row-groups x 2 key-halves), Q direct from L2,
// K LDS-staged dbuf, per-wave P with verified ((row&7)<<4) swizzle,
// exact defer-max, end-of-kernel (m,l,O) half-merge in LDS.
//
// ws layout (bytes):
//   VOFF: v  f16, tile-swizzled [256 tiles][64 rows][512B row, 16B-slot swz]  8 MB
//   KOFF: k  f16, same layout                                                  8 MB
//   QOFF: qT f16, per batch [64 tiles][256 c][64 n]  (plain, no swizzle)       8 MB
//   WOFF: W^T f16 [3][256 c][256 k]                                            384 KB

typedef _Float16 f16;
typedef __attribute__((ext_vector_type(8))) _Float16 f16x8;
typedef __attribute__((ext_vector_type(4))) float f32x4;
typedef __attribute__((ext_vector_type(4))) unsigned int u32x4;

#define MFMA16(a, b, c) __builtin_amdgcn_mfma_f32_16x16x32_f16((a), (b), (c), 0, 0, 0)

constexpr size_t VOFF = 0;
constexpr size_t KOFF = (size_t)8 << 20;
constexpr size_t QOFF = (size_t)16 << 20;
constexpr size_t WOFF = (size_t)24 << 20;

// ---------------------------------------------------------------- kernel 1
__global__ __launch_bounds__(256) void wt_kernel(const float* __restrict__ wv,
                                                 const float* __restrict__ wk,
                                                 const float* __restrict__ wq,
                                                 f16* __restrict__ wt) {
  int idx = blockIdx.x * 256 + threadIdx.x;
  int p = idx >> 16;
  int rem = idx & 65535;
  int c = rem >> 8, k = rem & 255;
  const float* w = (p == 0) ? wv : (p == 1) ? wk : wq;
  wt[idx] = (f16)w[k * 256 + c];
}

// ---------------------------------------------------------------- kernel 2
__global__ __launch_bounds__(256) void proj_kernel(const float* __restrict__ x,
                                                   uint8_t* __restrict__ ws) {
  __shared__ __align__(16) uint8_t xt[32768];
  __shared__ __align__(16) uint8_t ot[32768];

  const int tid = threadIdx.x;
  const int blk = blockIdx.x;
  const int lane = tid & 63, wid = tid >> 6;
  const int l15 = lane & 15, g = lane >> 4;

  {
    int r = tid >> 2, cb = tid & 3;
    const float* src = x + (size_t)(blk * 64 + r) * 256 + cb * 64;
    int sw = (r & 7) << 4;
#pragma unroll
    for (int jj = 0; jj < 8; ++jj) {
      float4 f0 = *(const float4*)(src + jj * 8);
      float4 f1 = *(const float4*)(src + jj * 8 + 4);
      f16x8 h;
      h[0] = (f16)f0.x; h[1] = (f16)f0.y; h[2] = (f16)f0.z; h[3] = (f16)f0.w;
      h[4] = (f16)f1.x; h[5] = (f16)f1.y; h[6] = (f16)f1.z; h[7] = (f16)f1.w;
      int addr = r * 512 + ((cb * 128 + jj * 16) ^ sw);
      *(f16x8*)(xt + addr) = h;
    }
  }
  __syncthreads();

  const f16* wtp = (const f16*)(ws + WOFF);
  const int arow = wid * 16 + l15;
  const int asw = (arow & 7) << 4;

  for (int p = 0; p < 3; ++p) {
    f32x4 o[16];
#pragma unroll
    for (int t = 0; t < 16; ++t) o[t] = (f32x4){0.f, 0.f, 0.f, 0.f};
    const f16* wp = wtp + p * 65536;

#pragma unroll
    for (int kc = 0; kc < 8; ++kc) {
      f16x8 a = *(const f16x8*)(xt + arow * 512 + ((kc * 64 + g * 16) ^ asw));
#pragma unroll
      for (int t = 0; t < 16; ++t) {
        int col = t * 16 + l15;
        f16x8 b = *(const f16x8*)(wp + col * 256 + kc * 32 + g * 8);
        o[t] = MFMA16(a, b, o[t]);
      }
    }

    __syncthreads();
#pragma unroll
    for (int t = 0; t < 16; ++t) {
#pragma unroll
      for (int r = 0; r < 4; ++r) {
        int prow = wid * 16 + g * 4 + r;
        int pcol = t * 16 + l15;
        int addr = prow * 512 + ((pcol * 2) ^ ((prow & 7) << 4));
        *(f16*)(ot + addr) = (f16)o[t][r];
      }
    }
    __syncthreads();

    if (p < 2) {
      uint8_t* dst = ws + (p == 0 ? VOFF : KOFF) + (size_t)blk * 32768;
#pragma unroll
      for (int jj = 0; jj < 8; ++jj) {
        u32x4 d = *(const u32x4*)(ot + jj * 4096 + tid * 16);
        *(u32x4*)(dst + jj * 4096 + tid * 16) = d;
      }
    } else {
      // qT: [c][64 n] plain layout (reads go直接 to L2, no bank concerns)
      int c = tid;
      int b2 = blk >> 6, kt2 = blk & 63;
      uint8_t* dst = ws + QOFF + (size_t)b2 * 2097152 + (size_t)kt2 * 32768 + c * 128;
#pragma unroll
      for (int jj = 0; jj < 8; ++jj) {
        u32x4 d;
#pragma unroll
        for (int q = 0; q < 4; ++q) {
          int r0 = jj * 8 + q * 2, r1 = r0 + 1;
          uint32_t lo = *(const uint16_t*)(ot + r0 * 512 + ((c * 2) ^ ((r0 & 7) << 4)));
          uint32_t hi = *(const uint16_t*)(ot + r1 * 512 + ((c * 2) ^ ((r1 & 7) << 4)));
          d[q] = lo | (hi << 16);
        }
        *(u32x4*)(dst + jj * 16) = d;
      }
    }
    __syncthreads();
  }
}

// ---------------------------------------------------------------- kernel 3
// 256 WGs x 512 threads. wave wid: rg=wid&3 (rows rg*16..+16), kh=wid>>2
// (keys kh*32..+32 of every tile). Each wave: private online softmax over
// its half-keys; final (m,l,O) merge between kh pairs via LDS.
// LDS: K dbuf 2*32K | P 8*2K  = 81920 B. Merge reuses K area.
__global__ __launch_bounds__(512, 2) void flash_kernel(const float* __restrict__ x,
                                                       const float* __restrict__ gptr,
                                                       float* __restrict__ out,
                                                       const uint8_t* __restrict__ ws) {
  extern __shared__ __align__(16) uint8_t lds[];
  const int tid = threadIdx.x, lane = tid & 63, wid = tid >> 6;
  const int l15 = lane & 15, g = lane >> 4;
  const int rg = wid & 3, kh = wid >> 2;

  int blk = blockIdx.x;
  int swz = (blk & 7) * 32 + (blk >> 3);
  int b = swz >> 6, rb = swz & 63;

  // V fragments (rows rg*16..+16), held in registers
  f16x8 vf[8];
  {
    int r = rg * 16 + l15;
    const uint8_t* vt = ws + VOFF + (size_t)(b * 64 + rb) * 32768 + r * 512;
    int sw = (r & 7) << 4;
#pragma unroll
    for (int cb = 0; cb < 8; ++cb)
      vf[cb] = *(const f16x8*)(vt + ((cb * 64 + g * 16) ^ sw));
  }

  const float gl2 = gptr[0] * 1.44269504088896f;

  f32x4 o[16];
#pragma unroll
  for (int t = 0; t < 16; ++t) o[t] = (f32x4){0.f, 0.f, 0.f, 0.f};
  float m[4] = {-1e30f, -1e30f, -1e30f, -1e30f};
  float l[4] = {0.f, 0.f, 0.f, 0.f};

  uint8_t* pw = lds + 65536 + wid * 2048;  // per-wave P [16 rows][128B], swizzled
  const uint8_t* ktile0 = ws + KOFF + (size_t)(b * 64) * 32768;
  const uint8_t* qtile0 = ws + QOFF + (size_t)b * 2097152;

  // prologue: stage K tile 0 (32KB / 512 threads = 4 x 16B each)
  {
    u32x4 st[4];
#pragma unroll
    for (int i = 0; i < 4; ++i) st[i] = *(const u32x4*)(ktile0 + i * 8192 + tid * 16);
#pragma unroll
    for (int i = 0; i < 4; ++i) *(u32x4*)(lds + i * 8192 + tid * 16) = st[i];
  }
  __syncthreads();

  u32x4 stk[4];
  for (int kt = 0; kt < 64; ++kt) {
    const int cur = kt & 1;
    const bool pre = (kt < 63);
    if (pre) {  // K prefetch: issue early, write after compute
      const uint8_t* kt1 = ktile0 + (size_t)(kt + 1) * 32768;
#pragma unroll
      for (int i = 0; i < 4; ++i) stk[i] = *(const u32x4*)(kt1 + i * 8192 + tid * 16);
    }
    // Q fragments for this tile: direct from global (L1/L2), issue early
    const uint8_t* qt = qtile0 + (size_t)kt * 32768;
    f16x8 qf[16];
#pragma unroll
    for (int t16 = 0; t16 < 16; ++t16) {
      int c = t16 * 16 + l15;
      qf[t16] = *(const f16x8*)(qt + c * 128 + kh * 64 + g * 16);
    }

    // ---- scores: S(16 x 32) = V(16x256) @ K_half^T ----
    const uint8_t* kbuf = lds + cur * 32768;
    f32x4 s[2];
    s[0] = (f32x4){0.f, 0.f, 0.f, 0.f};
    s[1] = (f32x4){0.f, 0.f, 0.f, 0.f};
#pragma unroll
    for (int cb = 0; cb < 8; ++cb) {
#pragma unroll
      for (int t = 0; t < 2; ++t) {
        int key = kh * 32 + t * 16 + l15;
        f16x8 kb =
            *(const f16x8*)(kbuf + key * 512 + ((cb * 64 + g * 16) ^ ((key & 7) << 4)));
        s[t] = MFMA16(vf[cb], kb, s[t]);
      }
    }

    // ---- online softmax over 32-key half ----
    float rm[4], rs[4];
#pragma unroll
    for (int r = 0; r < 4; ++r) {
      s[0][r] *= gl2;
      s[1][r] *= gl2;
      rm[r] = fmaxf(s[0][r], s[1][r]);
    }
#pragma unroll
    for (int msk = 1; msk < 16; msk <<= 1)
#pragma unroll
      for (int r = 0; r < 4; ++r) rm[r] = fmaxf(rm[r], __shfl_xor(rm[r], msk, 64));

    bool keep = (rm[0] <= m[0]) && (rm[1] <= m[1]) && (rm[2] <= m[2]) && (rm[3] <= m[3]);
    if (!__all(keep)) {  // exact defer: rescale only when a max actually grew
      float sc[4];
#pragma unroll
      for (int r = 0; r < 4; ++r) {
        float mn = fmaxf(m[r], rm[r]);
        sc[r] = __builtin_amdgcn_exp2f(m[r] - mn);
        m[r] = mn;
        l[r] *= sc[r];
      }
#pragma unroll
      for (int t = 0; t < 16; ++t)
#pragma unroll
        for (int r = 0; r < 4; ++r) o[t][r] *= sc[r];
    }

#pragma unroll
    for (int r = 0; r < 4; ++r) rs[r] = 0.f;
#pragma unroll
    for (int t = 0; t < 2; ++t) {
#pragma unroll
      for (int r = 0; r < 4; ++r) {
        float p = __builtin_amdgcn_exp2f(s[t][r] - m[r]);
        rs[r] += p;
        int prow = g * 4 + r, pcol = t * 16 + l15;
        *(f16*)(pw + prow * 128 + ((pcol * 2) ^ ((prow & 7) << 4))) = (f16)p;
      }
    }
#pragma unroll
    for (int msk = 1; msk < 16; msk <<= 1)
#pragma unroll
      for (int r = 0; r < 4; ++r) rs[r] += __shfl_xor(rs[r], msk, 64);
#pragma unroll
    for (int r = 0; r < 4; ++r) l[r] += rs[r];

    // ---- PV: O(16x256) += P(16x32) @ Q_half(32x256) ----
    f16x8 pa = *(const f16x8*)(pw + l15 * 128 + ((g * 16) ^ ((l15 & 7) << 4)));
#pragma unroll
    for (int t16 = 0; t16 < 16; ++t16) o[t16] = MFMA16(pa, qf[t16], o[t16]);

    if (pre) {
      uint8_t* nk = lds + (cur ^ 1) * 32768;
#pragma unroll
      for (int i = 0; i < 4; ++i) *(u32x4*)(nk + i * 8192 + tid * 16) = stk[i];
    }
    __syncthreads();
  }

  // ---- merge kh=1 partials into kh=0, write out ----
  if (kh == 1) {
    uint8_t* ob = lds + rg * 16384;
#pragma unroll
    for (int t16 = 0; t16 < 16; ++t16) *(f32x4*)(ob + t16 * 1024 + lane * 16) = o[t16];
    uint8_t* mlb = lds + 65536 + (4 + rg) * 2048;
    if (l15 == 0) {
#pragma unroll
      for (int r = 0; r < 4; ++r) {
        *(float*)(mlb + (g * 4 + r) * 8) = m[r];
        *(float*)(mlb + (g * 4 + r) * 8 + 4) = l[r];
      }
    }
  }
  __syncthreads();
  if (kh == 0) {
    const uint8_t* ob = lds + rg * 16384;
    const uint8_t* mlb = lds + 65536 + (4 + rg) * 2048;
    float a[4], bs[4], inv[4];
#pragma unroll
    for (int r = 0; r < 4; ++r) {
      float pm = *(const float*)(mlb + (g * 4 + r) * 8);
      float pl = *(const float*)(mlb + (g * 4 + r) * 8 + 4);
      float mn = fmaxf(m[r], pm);
      a[r] = __builtin_amdgcn_exp2f(m[r] - mn);
      bs[r] = __builtin_amdgcn_exp2f(pm - mn);
      inv[r] = 1.0f / (l[r] * a[r] + pl * bs[r]);
    }
#pragma unroll
    for (int t16 = 0; t16 < 16; ++t16) {
      f32x4 po = *(const f32x4*)(ob + t16 * 1024 + lane * 16);
#pragma unroll
      for (int r = 0; r < 4; ++r) {
        size_t grow = (size_t)b * 4096 + (size_t)rb * 64 + rg * 16 + g * 4 + r;
        size_t idx = grow * 256 + t16 * 16 + l15;
        out[idx] = (o[t16][r] * a[r] + po[r] * bs[r]) * inv[r] + x[idx];
      }
    }
  }
}

// ---------------------------------------------------------------- launch
extern "C" void kernel_launch(void* const* d_in, const int* in_sizes, int n_in,
                              void* d_out, int out_size, void* d_ws, size_t ws_size,
                              hipStream_t stream) {
  (void)in_sizes; (void)n_in; (void)out_size; (void)ws_size;
  const float* x = (const float*)d_in[0];
  const float* wv = (const float*)d_in[1];
  const float* wk = (const float*)d_in[2];
  const float* wq = (const float*)d_in[3];
  const float* gamma = (const float*)d_in[4];
  float* out = (float*)d_out;
  uint8_t* ws = (uint8_t*)d_ws;

  wt_kernel<<<768, 256, 0, stream>>>(wv, wk, wq, (f16*)(ws + WOFF));
  proj_kernel<<<256, 256, 0, stream>>>(x, ws);

  hipFuncSetAttribute((const void*)flash_kernel,
                      hipFuncAttributeMaxDynamicSharedMemorySize, 81920);
  flash_kernel<<<256, 512, 81920, stream>>>(x, gamma, out, ws);
}

// Round 3
// 218.670 us; speedup vs baseline: 1.5260x; 1.5260x over previous
//
#include <hip/hip_runtime.h>
#include <stdint.h>

// Round 3: 8-wave WG (4 row-groups x 2 key-halves), K AND Q double-buffered
// in LDS with reg-prefetch (one barrier/tile), conflict-free swizzles
// ((c&7)<<4 on Q, ((row>>2)&1)<<5 on per-wave P), setprio around MFMA,
// per-wave online softmax + end (m,l,O) merge. proj upgraded to 512 thr.
//
// ws layout (bytes):
//   VOFF: v  f16, tile-swizzled [256 tiles][64 rows][512B row, 16B-slot swz]  8 MB
//   KOFF: k  f16, same layout                                                  8 MB
//   QOFF: qT f16, per batch [64 tiles][256 c][128B, (c&7)<<4 swizzled]         8 MB
//   WOFF: W^T f16 [3][256 c][256 k]                                            384 KB

typedef _Float16 f16;
typedef __attribute__((ext_vector_type(8))) _Float16 f16x8;
typedef __attribute__((ext_vector_type(4))) float f32x4;
typedef __attribute__((ext_vector_type(4))) unsigned int u32x4;

#define MFMA16(a, b, c) __builtin_amdgcn_mfma_f32_16x16x32_f16((a), (b), (c), 0, 0, 0)

constexpr size_t VOFF = 0;
constexpr size_t KOFF = (size_t)8 << 20;
constexpr size_t QOFF = (size_t)16 << 20;
constexpr size_t WOFF = (size_t)24 << 20;

// ---------------------------------------------------------------- kernel 1
__global__ __launch_bounds__(256) void wt_kernel(const float* __restrict__ wv,
                                                 const float* __restrict__ wk,
                                                 const float* __restrict__ wq,
                                                 f16* __restrict__ wt) {
  int idx = blockIdx.x * 256 + threadIdx.x;
  int p = idx >> 16;
  int rem = idx & 65535;
  int c = rem >> 8, k = rem & 255;
  const float* w = (p == 0) ? wv : (p == 1) ? wk : wq;
  wt[idx] = (f16)w[k * 256 + c];
}

// ---------------------------------------------------------------- kernel 2
// 512 threads, 8 waves: rg=wid&3 (16-row block), ch=wid>>2 (128-col half).
__global__ __launch_bounds__(512, 2) void proj_kernel(const float* __restrict__ x,
                                                      uint8_t* __restrict__ ws) {
  __shared__ __align__(16) uint8_t xt[32768];
  __shared__ __align__(16) uint8_t ot[32768];

  const int tid = threadIdx.x;
  const int blk = blockIdx.x;
  const int lane = tid & 63, wid = tid >> 6;
  const int l15 = lane & 15, g = lane >> 4;
  const int rg = wid & 3, ch = wid >> 2;

  // ---- stage x tile: thread handles row r, 32 cols at c0 ----
  {
    int r = tid >> 3, c0 = (tid & 7) * 32;
    const float* src = x + (size_t)(blk * 64 + r) * 256 + c0;
    int sw = (r & 7) << 4;
#pragma unroll
    for (int j = 0; j < 4; ++j) {
      float4 f0 = *(const float4*)(src + j * 8);
      float4 f1 = *(const float4*)(src + j * 8 + 4);
      f16x8 h;
      h[0] = (f16)f0.x; h[1] = (f16)f0.y; h[2] = (f16)f0.z; h[3] = (f16)f0.w;
      h[4] = (f16)f1.x; h[5] = (f16)f1.y; h[6] = (f16)f1.z; h[7] = (f16)f1.w;
      *(f16x8*)(xt + r * 512 + ((c0 * 2 + j * 16) ^ sw)) = h;
    }
  }
  __syncthreads();

  const f16* wtp = (const f16*)(ws + WOFF);
  const int arow = rg * 16 + l15;
  const int asw = (arow & 7) << 4;

  for (int p = 0; p < 3; ++p) {
    f32x4 o[8];
#pragma unroll
    for (int t = 0; t < 8; ++t) o[t] = (f32x4){0.f, 0.f, 0.f, 0.f};
    const f16* wp = wtp + p * 65536;

#pragma unroll
    for (int kc = 0; kc < 8; ++kc) {
      f16x8 a = *(const f16x8*)(xt + arow * 512 + ((kc * 64 + g * 16) ^ asw));
#pragma unroll
      for (int t = 0; t < 8; ++t) {
        int col = ch * 128 + t * 16 + l15;
        f16x8 b = *(const f16x8*)(wp + col * 256 + kc * 32 + g * 8);
        o[t] = MFMA16(a, b, o[t]);
      }
    }

    __syncthreads();
#pragma unroll
    for (int t = 0; t < 8; ++t) {
#pragma unroll
      for (int r = 0; r < 4; ++r) {
        int prow = rg * 16 + g * 4 + r;
        int pcol = ch * 128 + t * 16 + l15;
        int addr = prow * 512 + ((pcol * 2) ^ ((prow & 7) << 4));
        *(f16*)(ot + addr) = (f16)o[t][r];
      }
    }
    __syncthreads();

    if (p < 2) {
      uint8_t* dst = ws + (p == 0 ? VOFF : KOFF) + (size_t)blk * 32768;
#pragma unroll
      for (int jj = 0; jj < 4; ++jj) {
        u32x4 d = *(const u32x4*)(ot + jj * 8192 + tid * 16);
        *(u32x4*)(dst + jj * 8192 + tid * 16) = d;
      }
    } else {
      // qT: [c][128B] rows, slot-swizzled by (c&7)<<4
      int c = tid >> 1, half = tid & 1;
      int b2 = blk >> 6, kt2 = blk & 63;
      uint8_t* dst = ws + QOFF + (size_t)b2 * 2097152 + (size_t)kt2 * 32768 + c * 128;
#pragma unroll
      for (int jj2 = 0; jj2 < 4; ++jj2) {
        int jj = half * 4 + jj2;
        u32x4 d;
#pragma unroll
        for (int q = 0; q < 4; ++q) {
          int r0 = jj * 8 + q * 2, r1 = r0 + 1;
          uint32_t lo = *(const uint16_t*)(ot + r0 * 512 + ((c * 2) ^ ((r0 & 7) << 4)));
          uint32_t hi = *(const uint16_t*)(ot + r1 * 512 + ((c * 2) ^ ((r1 & 7) << 4)));
          d[q] = lo | (hi << 16);
        }
        *(u32x4*)(dst + ((jj * 16) ^ ((c & 7) << 4))) = d;
      }
    }
    __syncthreads();
  }
}

// ---------------------------------------------------------------- kernel 3
// 256 WGs x 512 threads. rg=wid&3 (rows rg*16..+16), kh=wid>>2 (keys kh*32..+32).
// LDS: K dbuf 2*32K @0 | Q dbuf 2*32K @65536 | P 8*1K @131072 = 139264 B.
__global__ __launch_bounds__(512, 2) void flash_kernel(const float* __restrict__ x,
                                                       const float* __restrict__ gptr,
                                                       float* __restrict__ out,
                                                       const uint8_t* __restrict__ ws) {
  extern __shared__ __align__(16) uint8_t lds[];
  const int tid = threadIdx.x, lane = tid & 63, wid = tid >> 6;
  const int l15 = lane & 15, g = lane >> 4;
  const int rg = wid & 3, kh = wid >> 2;

  int blk = blockIdx.x;
  int swz = (blk & 7) * 32 + (blk >> 3);
  int b = swz >> 6, rb = swz & 63;

  // V fragments (rows rg*16..+16), in registers for the whole kernel
  f16x8 vf[8];
  {
    int r = rg * 16 + l15;
    const uint8_t* vt = ws + VOFF + (size_t)(b * 64 + rb) * 32768 + r * 512;
    int sw = (r & 7) << 4;
#pragma unroll
    for (int cb = 0; cb < 8; ++cb)
      vf[cb] = *(const f16x8*)(vt + ((cb * 64 + g * 16) ^ sw));
  }

  const float gl2 = gptr[0] * 1.44269504088896f;

  f32x4 o[16];
#pragma unroll
  for (int t = 0; t < 16; ++t) o[t] = (f32x4){0.f, 0.f, 0.f, 0.f};
  float m[4] = {-1e30f, -1e30f, -1e30f, -1e30f};
  float l[4] = {0.f, 0.f, 0.f, 0.f};

  uint8_t* pw = lds + 131072 + wid * 1024;  // per-wave P [16 rows][64B]
  const uint8_t* ktile0 = ws + KOFF + (size_t)(b * 64) * 32768;
  const uint8_t* qtile0 = ws + QOFF + (size_t)b * 2097152;

  // prologue: stage K+Q tile 0 (each 32KB / 512 threads = 4 x 16B)
  {
    u32x4 sk[4], sq[4];
#pragma unroll
    for (int i = 0; i < 4; ++i) {
      sk[i] = *(const u32x4*)(ktile0 + i * 8192 + tid * 16);
      sq[i] = *(const u32x4*)(qtile0 + i * 8192 + tid * 16);
    }
#pragma unroll
    for (int i = 0; i < 4; ++i) {
      *(u32x4*)(lds + i * 8192 + tid * 16) = sk[i];
      *(u32x4*)(lds + 65536 + i * 8192 + tid * 16) = sq[i];
    }
  }
  __syncthreads();

  u32x4 stk[4], stq[4];
  for (int kt = 0; kt < 64; ++kt) {
    const int cur = kt & 1;
    const bool pre = (kt < 63);
    if (pre) {  // issue next-tile loads early; written to LDS after compute
      const uint8_t* kt1 = ktile0 + (size_t)(kt + 1) * 32768;
      const uint8_t* qt1 = qtile0 + (size_t)(kt + 1) * 32768;
#pragma unroll
      for (int i = 0; i < 4; ++i) {
        stk[i] = *(const u32x4*)(kt1 + i * 8192 + tid * 16);
        stq[i] = *(const u32x4*)(qt1 + i * 8192 + tid * 16);
      }
    }
    const uint8_t* kbuf = lds + cur * 32768;
    const uint8_t* qbuf = lds + 65536 + cur * 32768;

    // ---- scores: S(16 x 32) = V(16x256) @ K_half^T ----
    f32x4 s[2];
    s[0] = (f32x4){0.f, 0.f, 0.f, 0.f};
    s[1] = (f32x4){0.f, 0.f, 0.f, 0.f};
    __builtin_amdgcn_s_setprio(1);
#pragma unroll
    for (int cb = 0; cb < 8; ++cb) {
#pragma unroll
      for (int t = 0; t < 2; ++t) {
        int key = kh * 32 + t * 16 + l15;
        f16x8 kb =
            *(const f16x8*)(kbuf + key * 512 + ((cb * 64 + g * 16) ^ ((key & 7) << 4)));
        s[t] = MFMA16(vf[cb], kb, s[t]);
      }
    }
    __builtin_amdgcn_s_setprio(0);

    // ---- online softmax over this wave's 32 keys ----
    float rm[4], rs[4];
#pragma unroll
    for (int r = 0; r < 4; ++r) {
      s[0][r] *= gl2;
      s[1][r] *= gl2;
      rm[r] = fmaxf(s[0][r], s[1][r]);
    }
#pragma unroll
    for (int msk = 1; msk < 16; msk <<= 1)
#pragma unroll
      for (int r = 0; r < 4; ++r) rm[r] = fmaxf(rm[r], __shfl_xor(rm[r], msk, 64));

    bool keep = (rm[0] <= m[0]) && (rm[1] <= m[1]) && (rm[2] <= m[2]) && (rm[3] <= m[3]);
    if (!__all(keep)) {  // exact defer-max: rescale only when a row max grew
      float sc[4];
#pragma unroll
      for (int r = 0; r < 4; ++r) {
        float mn = fmaxf(m[r], rm[r]);
        sc[r] = __builtin_amdgcn_exp2f(m[r] - mn);
        m[r] = mn;
        l[r] *= sc[r];
      }
#pragma unroll
      for (int t = 0; t < 16; ++t)
#pragma unroll
        for (int r = 0; r < 4; ++r) o[t][r] *= sc[r];
    }

#pragma unroll
    for (int r = 0; r < 4; ++r) rs[r] = 0.f;
#pragma unroll
    for (int t = 0; t < 2; ++t) {
#pragma unroll
      for (int r = 0; r < 4; ++r) {
        float p = __builtin_amdgcn_exp2f(s[t][r] - m[r]);
        rs[r] += p;
        int prow = g * 4 + r, pcol = t * 16 + l15;  // pcol in 0..31
        *(f16*)(pw + prow * 64 + ((pcol * 2) ^ (((prow >> 2) & 1) << 5))) = (f16)p;
      }
    }
#pragma unroll
    for (int msk = 1; msk < 16; msk <<= 1)
#pragma unroll
      for (int r = 0; r < 4; ++r) rs[r] += __shfl_xor(rs[r], msk, 64);
#pragma unroll
    for (int r = 0; r < 4; ++r) l[r] += rs[r];

    // ---- PV: O(16x256) += P(16x32) @ Q_half(32x256) ----
    f16x8 pa = *(const f16x8*)(pw + l15 * 64 + ((g * 16) ^ (((l15 >> 2) & 1) << 5)));
    __builtin_amdgcn_s_setprio(1);
#pragma unroll
    for (int t16 = 0; t16 < 16; ++t16) {
      int c = t16 * 16 + l15;
      f16x8 qf =
          *(const f16x8*)(qbuf + c * 128 + ((kh * 64 + g * 16) ^ ((c & 7) << 4)));
      o[t16] = MFMA16(pa, qf, o[t16]);
    }
    __builtin_amdgcn_s_setprio(0);

    if (pre) {  // write prefetched tile into the other buffer
      uint8_t* nk = lds + (cur ^ 1) * 32768;
      uint8_t* nq = lds + 65536 + (cur ^ 1) * 32768;
#pragma unroll
      for (int i = 0; i < 4; ++i) {
        *(u32x4*)(nk + i * 8192 + tid * 16) = stk[i];
        *(u32x4*)(nq + i * 8192 + tid * 16) = stq[i];
      }
    }
    __syncthreads();
  }

  // ---- merge kh=1 partials into kh=0, write out ----
  if (kh == 1) {
    uint8_t* ob = lds + rg * 16384;  // reuse K dbuf area
#pragma unroll
    for (int t16 = 0; t16 < 16; ++t16) *(f32x4*)(ob + t16 * 1024 + lane * 16) = o[t16];
    uint8_t* mlb = lds + 131072 + (4 + rg) * 1024;  // own P buffer
    if (l15 == 0) {
#pragma unroll
      for (int r = 0; r < 4; ++r) {
        *(float*)(mlb + (g * 4 + r) * 8) = m[r];
        *(float*)(mlb + (g * 4 + r) * 8 + 4) = l[r];
      }
    }
  }
  __syncthreads();
  if (kh == 0) {
    const uint8_t* ob = lds + rg * 16384;
    const uint8_t* mlb = lds + 131072 + (4 + rg) * 1024;
    float a[4], bs[4], inv[4];
#pragma unroll
    for (int r = 0; r < 4; ++r) {
      float pm = *(const float*)(mlb + (g * 4 + r) * 8);
      float pl = *(const float*)(mlb + (g * 4 + r) * 8 + 4);
      float mn = fmaxf(m[r], pm);
      a[r] = __builtin_amdgcn_exp2f(m[r] - mn);
      bs[r] = __builtin_amdgcn_exp2f(pm - mn);
      inv[r] = 1.0f / (l[r] * a[r] + pl * bs[r]);
    }
#pragma unroll
    for (int t16 = 0; t16 < 16; ++t16) {
      f32x4 po = *(const f32x4*)(ob + t16 * 1024 + lane * 16);
#pragma unroll
      for (int r = 0; r < 4; ++r) {
        size_t grow = (size_t)b * 4096 + (size_t)rb * 64 + rg * 16 + g * 4 + r;
        size_t idx = grow * 256 + t16 * 16 + l15;
        out[idx] = (o[t16][r] * a[r] + po[r] * bs[r]) * inv[r] + x[idx];
      }
    }
  }
}

// ---------------------------------------------------------------- launch
extern "C" void kernel_launch(void* const* d_in, const int* in_sizes, int n_in,
                              void* d_out, int out_size, void* d_ws, size_t ws_size,
                              hipStream_t stream) {
  (void)in_sizes; (void)n_in; (void)out_size; (void)ws_size;
  const float* x = (const float*)d_in[0];
  const float* wv = (const float*)d_in[1];
  const float* wk = (const float*)d_in[2];
  const float* wq = (const float*)d_in[3];
  const float* gamma = (const float*)d_in[4];
  float* out = (float*)d_out;
  uint8_t* ws = (uint8_t*)d_ws;

  wt_kernel<<<768, 256, 0, stream>>>(wv, wk, wq, (f16*)(ws + WOFF));
  proj_kernel<<<256, 512, 0, stream>>>(x, ws);

  hipFuncSetAttribute((const void*)flash_kernel,
                      hipFuncAttributeMaxDynamicSharedMemorySize, 139264);
  flash_kernel<<<256, 512, 139264, stream>>>(x, gamma, out, ws);
}

// Round 5
// 201.535 us; speedup vs baseline: 1.6558x; 1.0850x over previous
//
#include <hip/hip_runtime.h>
#include <stdint.h>

// Round 5 (= R4 with compile fix): swapped QK^T (S^T = mfma(K,V)) -> row-local
// softmax, P stays in registers (cvt_pkrtz + shfl, no LDS P, no conflicts).
// K/Q staged via global_load_lds (linear dest), 1 barrier/tile, dense MFMA
// clusters + setprio.
//
// ws layout (bytes):
//   VOFF: v  f16, tile-swizzled [256 tiles][64 rows][512B row, 16B-slot swz]  8 MB
//   KOFF: k  f16, same layout                                                  8 MB
//   QOFF: qT f16, per batch [64 tiles][256 c][128B, (c&7)<<4 swizzled]         8 MB
//   WOFF: W^T f16 [3][256 c][256 k]                                            384 KB

typedef _Float16 f16;
typedef __attribute__((ext_vector_type(8))) _Float16 f16x8;
typedef __attribute__((ext_vector_type(4))) float f32x4;
typedef __attribute__((ext_vector_type(4))) unsigned int u32x4;

#define MFMA16(a, b, c) __builtin_amdgcn_mfma_f32_16x16x32_f16((a), (b), (c), 0, 0, 0)

constexpr size_t VOFF = 0;
constexpr size_t KOFF = (size_t)8 << 20;
constexpr size_t QOFF = (size_t)16 << 20;
constexpr size_t WOFF = (size_t)24 << 20;

__device__ inline void gll16(const void* g, void* l) {
  __builtin_amdgcn_global_load_lds(
      (const __attribute__((address_space(1))) uint32_t*)g,
      (__attribute__((address_space(3))) uint32_t*)l, 16, 0, 0);
}

__device__ inline uint32_t pkf16(float a, float b) {
  union { decltype(__builtin_amdgcn_cvt_pkrtz(0.f, 0.f)) h; uint32_t u; } cv;
  cv.h = __builtin_amdgcn_cvt_pkrtz(a, b);
  return cv.u;
}

// ---------------------------------------------------------------- kernel 1
__global__ __launch_bounds__(256) void wt_kernel(const float* __restrict__ wv,
                                                 const float* __restrict__ wk,
                                                 const float* __restrict__ wq,
                                                 f16* __restrict__ wt) {
  int idx = blockIdx.x * 256 + threadIdx.x;
  int p = idx >> 16;
  int rem = idx & 65535;
  int c = rem >> 8, k = rem & 255;
  const float* w = (p == 0) ? wv : (p == 1) ? wk : wq;
  wt[idx] = (f16)w[k * 256 + c];
}

// ---------------------------------------------------------------- kernel 2
// 512 threads, 8 waves: rg=wid&3 (16-row block), ch=wid>>2 (128-col half).
__global__ __launch_bounds__(512, 2) void proj_kernel(const float* __restrict__ x,
                                                      uint8_t* __restrict__ ws) {
  __shared__ __align__(16) uint8_t xt[32768];
  __shared__ __align__(16) uint8_t ot[32768];

  const int tid = threadIdx.x;
  const int blk = blockIdx.x;
  const int lane = tid & 63, wid = tid >> 6;
  const int l15 = lane & 15, g = lane >> 4;
  const int rg = wid & 3, ch = wid >> 2;

  {
    int r = tid >> 3, c0 = (tid & 7) * 32;
    const float* src = x + (size_t)(blk * 64 + r) * 256 + c0;
    int sw = (r & 7) << 4;
#pragma unroll
    for (int j = 0; j < 4; ++j) {
      float4 f0 = *(const float4*)(src + j * 8);
      float4 f1 = *(const float4*)(src + j * 8 + 4);
      f16x8 h;
      h[0] = (f16)f0.x; h[1] = (f16)f0.y; h[2] = (f16)f0.z; h[3] = (f16)f0.w;
      h[4] = (f16)f1.x; h[5] = (f16)f1.y; h[6] = (f16)f1.z; h[7] = (f16)f1.w;
      *(f16x8*)(xt + r * 512 + ((c0 * 2 + j * 16) ^ sw)) = h;
    }
  }
  __syncthreads();

  const f16* wtp = (const f16*)(ws + WOFF);
  const int arow = rg * 16 + l15;
  const int asw = (arow & 7) << 4;

  for (int p = 0; p < 3; ++p) {
    f32x4 o[8];
#pragma unroll
    for (int t = 0; t < 8; ++t) o[t] = (f32x4){0.f, 0.f, 0.f, 0.f};
    const f16* wp = wtp + p * 65536;

#pragma unroll
    for (int kc = 0; kc < 8; ++kc) {
      f16x8 a = *(const f16x8*)(xt + arow * 512 + ((kc * 64 + g * 16) ^ asw));
#pragma unroll
      for (int t = 0; t < 8; ++t) {
        int col = ch * 128 + t * 16 + l15;
        f16x8 b = *(const f16x8*)(wp + col * 256 + kc * 32 + g * 8);
        o[t] = MFMA16(a, b, o[t]);
      }
    }

    __syncthreads();
#pragma unroll
    for (int t = 0; t < 8; ++t) {
#pragma unroll
      for (int r = 0; r < 4; ++r) {
        int prow = rg * 16 + g * 4 + r;
        int pcol = ch * 128 + t * 16 + l15;
        int addr = prow * 512 + ((pcol * 2) ^ ((prow & 7) << 4));
        *(f16*)(ot + addr) = (f16)o[t][r];
      }
    }
    __syncthreads();

    if (p < 2) {
      uint8_t* dst = ws + (p == 0 ? VOFF : KOFF) + (size_t)blk * 32768;
#pragma unroll
      for (int jj = 0; jj < 4; ++jj) {
        u32x4 d = *(const u32x4*)(ot + jj * 8192 + tid * 16);
        *(u32x4*)(dst + jj * 8192 + tid * 16) = d;
      }
    } else {
      // qT: [c][128B] rows, 16B-slot swizzle (c&7)<<4
      int c = tid >> 1, half = tid & 1;
      int b2 = blk >> 6, kt2 = blk & 63;
      uint8_t* dst = ws + QOFF + (size_t)b2 * 2097152 + (size_t)kt2 * 32768 + c * 128;
#pragma unroll
      for (int jj2 = 0; jj2 < 4; ++jj2) {
        int jj = half * 4 + jj2;
        u32x4 d;
#pragma unroll
        for (int q = 0; q < 4; ++q) {
          int r0 = jj * 8 + q * 2, r1 = r0 + 1;
          uint32_t lo = *(const uint16_t*)(ot + r0 * 512 + ((c * 2) ^ ((r0 & 7) << 4)));
          uint32_t hi = *(const uint16_t*)(ot + r1 * 512 + ((c * 2) ^ ((r1 & 7) << 4)));
          d[q] = lo | (hi << 16);
        }
        *(u32x4*)(dst + ((jj * 16) ^ ((c & 7) << 4))) = d;
      }
    }
    __syncthreads();
  }
}

// ---------------------------------------------------------------- kernel 3
// 256 WGs x 512 thr. rg=wid&3 (rows rg*16..+16), kh=wid>>2 (keys kh*32..+32).
// LDS: K dbuf 2*32K @0 | Q dbuf 2*32K @65536 = 131072 B. P lives in registers.
__global__ __launch_bounds__(512, 2) void flash_kernel(const float* __restrict__ x,
                                                       const float* __restrict__ gptr,
                                                       float* __restrict__ out,
                                                       const uint8_t* __restrict__ ws) {
  extern __shared__ __align__(16) uint8_t lds[];
  const int tid = threadIdx.x, lane = tid & 63, wid = tid >> 6;
  const int l15 = lane & 15, g = lane >> 4;
  const int rg = wid & 3, kh = wid >> 2;

  int blk = blockIdx.x;
  int swz = (blk & 7) * 32 + (blk >> 3);
  int b = swz >> 6, rb = swz & 63;

  const uint8_t* ktile0 = ws + KOFF + (size_t)(b * 64) * 32768;
  const uint8_t* qtile0 = ws + QOFF + (size_t)b * 2097152;

  // prologue: stage tile 0 via global_load_lds (linear dest = base+lane*16)
#pragma unroll
  for (int i = 0; i < 4; ++i) {
    gll16(ktile0 + i * 8192 + tid * 16, lds + i * 8192 + wid * 1024);
    gll16(qtile0 + i * 8192 + tid * 16, lds + 65536 + i * 8192 + wid * 1024);
  }

  // V fragments (rows rg*16..+16), registers for the whole kernel (B-operand)
  f16x8 vf[8];
  {
    int r = rg * 16 + l15;
    const uint8_t* vt = ws + VOFF + (size_t)(b * 64 + rb) * 32768 + r * 512;
    int sw = (r & 7) << 4;
#pragma unroll
    for (int cb = 0; cb < 8; ++cb)
      vf[cb] = *(const f16x8*)(vt + ((cb * 64 + g * 16) ^ sw));
  }

  const float gl2 = gptr[0] * 1.44269504088896f;

  f32x4 o[16];
#pragma unroll
  for (int t = 0; t < 16; ++t) o[t] = (f32x4){0.f, 0.f, 0.f, 0.f};
  float m = -1e30f, l = 0.f;  // per-lane: row = l15 (uniform across g)

  const int rbase = (lane & 48) + ((lane & 48) >> 2);  // g*16 + g*4
  const int slo = ((lane >> 4) & 1) * 32 + (lane & 15);
  const int shi = slo + 16;
  const bool thi = (lane & 32) != 0;  // g>>1

  for (int kt = 0; kt < 64; ++kt) {
    const int cur = kt & 1;
    asm volatile("s_waitcnt vmcnt(0)" ::: "memory");
    __syncthreads();  // tile kt staged; buffers from kt-1 free for reuse

    if (kt < 63) {  // issue next tile -> other buffer (drains at next barrier)
      const uint8_t* kt1 = ktile0 + (size_t)(kt + 1) * 32768;
      const uint8_t* qt1 = qtile0 + (size_t)(kt + 1) * 32768;
      uint8_t* nk = lds + (cur ^ 1) * 32768;
      uint8_t* nq = lds + 65536 + (cur ^ 1) * 32768;
#pragma unroll
      for (int i = 0; i < 4; ++i) {
        gll16(kt1 + i * 8192 + tid * 16, nk + i * 8192 + wid * 1024);
        gll16(qt1 + i * 8192 + tid * 16, nq + i * 8192 + wid * 1024);
      }
    }
    const uint8_t* kbuf = lds + cur * 32768;
    const uint8_t* qbuf = lds + 65536 + cur * 32768;

    // ---- swapped scores: S^T(32key x 16row) = K_half @ V^T ----
    f32x4 s0 = (f32x4){0.f, 0.f, 0.f, 0.f};
    f32x4 s1 = (f32x4){0.f, 0.f, 0.f, 0.f};
    const int key0 = kh * 32 + l15;
    const int ksw = (l15 & 7) << 4;
    __builtin_amdgcn_s_setprio(1);
#pragma unroll
    for (int kc = 0; kc < 8; ++kc) {
      f16x8 ka0 = *(const f16x8*)(kbuf + key0 * 512 + ((kc * 64 + g * 16) ^ ksw));
      f16x8 ka1 = *(const f16x8*)(kbuf + (key0 + 16) * 512 + ((kc * 64 + g * 16) ^ ksw));
      s0 = MFMA16(ka0, vf[kc], s0);
      s1 = MFMA16(ka1, vf[kc], s1);
    }
    __builtin_amdgcn_s_setprio(0);

    // Q fragments for PV: issue now, latency hides under softmax
    f16x8 qf[16];
#pragma unroll
    for (int t16 = 0; t16 < 16; ++t16) {
      int c = t16 * 16 + l15;
      qf[t16] = *(const f16x8*)(qbuf + c * 128 + ((kh * 64 + g * 16) ^ ((c & 7) << 4)));
    }

    // ---- softmax: lane owns row l15; keys kh*32 + {t*16 + g*4 + r} ----
    float p[8];
#pragma unroll
    for (int r = 0; r < 4; ++r) {
      p[r] = s0[r] * gl2;
      p[4 + r] = s1[r] * gl2;
    }
    float rm = fmaxf(fmaxf(fmaxf(p[0], p[1]), fmaxf(p[2], p[3])),
                     fmaxf(fmaxf(p[4], p[5]), fmaxf(p[6], p[7])));
    rm = fmaxf(rm, __shfl_xor(rm, 16, 64));
    rm = fmaxf(rm, __shfl_xor(rm, 32, 64));

    if (!__all(rm <= m)) {  // exact defer-max
      float mn = fmaxf(m, rm);
      float sc = __builtin_amdgcn_exp2f(m - mn);
      m = mn;
      l *= sc;
      float sc0 = __shfl(sc, rbase + 0, 64);
      float sc1 = __shfl(sc, rbase + 1, 64);
      float sc2 = __shfl(sc, rbase + 2, 64);
      float sc3 = __shfl(sc, rbase + 3, 64);
#pragma unroll
      for (int t = 0; t < 16; ++t) {
        o[t][0] *= sc0; o[t][1] *= sc1; o[t][2] *= sc2; o[t][3] *= sc3;
      }
    }

    float rs = 0.f;
#pragma unroll
    for (int i = 0; i < 8; ++i) {
      p[i] = __builtin_amdgcn_exp2f(p[i] - m);
      rs += p[i];
    }
    rs += __shfl_xor(rs, 16, 64);
    rs += __shfl_xor(rs, 32, 64);
    l += rs;

    // ---- build PV A-frag in-register: need P[l15][g*8+j] ----
    uint32_t pk00 = pkf16(p[0], p[1]), pk01 = pkf16(p[2], p[3]);
    uint32_t pk10 = pkf16(p[4], p[5]), pk11 = pkf16(p[6], p[7]);
    uint32_t a0l = __shfl(pk00, slo, 64), a0h = __shfl(pk10, slo, 64);
    uint32_t a1l = __shfl(pk01, slo, 64), a1h = __shfl(pk11, slo, 64);
    uint32_t a2l = __shfl(pk00, shi, 64), a2h = __shfl(pk10, shi, 64);
    uint32_t a3l = __shfl(pk01, shi, 64), a3h = __shfl(pk11, shi, 64);
    union { uint32_t u[4]; f16x8 v; } pu;
    pu.u[0] = thi ? a0h : a0l;
    pu.u[1] = thi ? a1h : a1l;
    pu.u[2] = thi ? a2h : a2l;
    pu.u[3] = thi ? a3h : a3l;
    f16x8 pa = pu.v;

    // ---- PV: O(16x256) += P(16x32) @ Q_half(32x256), all-register ----
    __builtin_amdgcn_s_setprio(1);
#pragma unroll
    for (int t16 = 0; t16 < 16; ++t16) o[t16] = MFMA16(pa, qf[t16], o[t16]);
    __builtin_amdgcn_s_setprio(0);
  }

  __syncthreads();  // loop done; LDS free for the merge

  // ---- merge kh=1 partials into kh=0, write out ----
  if (kh == 1) {
    uint8_t* ob = lds + rg * 16384;
#pragma unroll
    for (int t16 = 0; t16 < 16; ++t16) *(f32x4*)(ob + t16 * 1024 + lane * 16) = o[t16];
    if (g == 0) {
      uint8_t* mlb = lds + 65536 + rg * 128;
      *(float*)(mlb + l15 * 8) = m;
      *(float*)(mlb + l15 * 8 + 4) = l;
    }
  }
  __syncthreads();
  if (kh == 0) {
    const uint8_t* ob = lds + rg * 16384;
    const uint8_t* mlb = lds + 65536 + rg * 128;
    float pm = *(const float*)(mlb + l15 * 8);
    float pl = *(const float*)(mlb + l15 * 8 + 4);
    float mn = fmaxf(m, pm);
    float a = __builtin_amdgcn_exp2f(m - mn);
    float bs = __builtin_amdgcn_exp2f(pm - mn);
    float inv = 1.0f / (l * a + pl * bs);
    float ar[4], br[4], ir[4];
#pragma unroll
    for (int r = 0; r < 4; ++r) {
      ar[r] = __shfl(a, rbase + r, 64);
      br[r] = __shfl(bs, rbase + r, 64);
      ir[r] = __shfl(inv, rbase + r, 64);
    }
#pragma unroll
    for (int t16 = 0; t16 < 16; ++t16) {
      f32x4 po = *(const f32x4*)(ob + t16 * 1024 + lane * 16);
#pragma unroll
      for (int r = 0; r < 4; ++r) {
        size_t grow = (size_t)b * 4096 + (size_t)rb * 64 + rg * 16 + g * 4 + r;
        size_t idx = grow * 256 + t16 * 16 + l15;
        out[idx] = (o[t16][r] * ar[r] + po[r] * br[r]) * ir[r] + x[idx];
      }
    }
  }
}

// ---------------------------------------------------------------- launch
extern "C" void kernel_launch(void* const* d_in, const int* in_sizes, int n_in,
                              void* d_out, int out_size, void* d_ws, size_t ws_size,
                              hipStream_t stream) {
  (void)in_sizes; (void)n_in; (void)out_size; (void)ws_size;
  const float* x = (const float*)d_in[0];
  const float* wv = (const float*)d_in[1];
  const float* wk = (const float*)d_in[2];
  const float* wq = (const float*)d_in[3];
  const float* gamma = (const float*)d_in[4];
  float* out = (float*)d_out;
  uint8_t* ws = (uint8_t*)d_ws;

  wt_kernel<<<768, 256, 0, stream>>>(wv, wk, wq, (f16*)(ws + WOFF));
  proj_kernel<<<256, 512, 0, stream>>>(x, ws);

  (void)hipFuncSetAttribute((const void*)flash_kernel,
                            hipFuncAttributeMaxDynamicSharedMemorySize, 131072);
  flash_kernel<<<256, 512, 131072, stream>>>(x, gamma, out, ws);
}

// Round 6
// 152.019 us; speedup vs baseline: 2.1951x; 1.3257x over previous
//
#include <hip/hip_runtime.h>
#include <stdint.h>

// Round 6: T3/T4 schedule on flash (raw s_barrier + counted vmcnt(4), K/Q
// staggered into two half-size sync points per tile, batch-issued ds_reads
// pinned via sched_barrier). proj: W^T staged in LDS (swizzled image).
//
// ws layout (bytes):
//   VOFF: v  f16, tile-swizzled [256 tiles][64 rows][512B row, 16B-slot swz]  8 MB
//   KOFF: k  f16, same layout                                                  8 MB
//   QOFF: qT f16, per batch [64 tiles][256 c][128B, (c&7)<<4 swizzled]         8 MB
//   WOFF: W^T f16 [3][256 c][256 k]                                            384 KB

typedef _Float16 f16;
typedef __attribute__((ext_vector_type(8))) _Float16 f16x8;
typedef __attribute__((ext_vector_type(4))) float f32x4;
typedef __attribute__((ext_vector_type(4))) unsigned int u32x4;

#define MFMA16(a, b, c) __builtin_amdgcn_mfma_f32_16x16x32_f16((a), (b), (c), 0, 0, 0)

constexpr size_t VOFF = 0;
constexpr size_t KOFF = (size_t)8 << 20;
constexpr size_t QOFF = (size_t)16 << 20;
constexpr size_t WOFF = (size_t)24 << 20;

__device__ inline void gll16(const void* g, void* l) {
  __builtin_amdgcn_global_load_lds(
      (const __attribute__((address_space(1))) uint32_t*)g,
      (__attribute__((address_space(3))) uint32_t*)l, 16, 0, 0);
}

__device__ inline uint32_t pkf16(float a, float b) {
  union { decltype(__builtin_amdgcn_cvt_pkrtz(0.f, 0.f)) h; uint32_t u; } cv;
  cv.h = __builtin_amdgcn_cvt_pkrtz(a, b);
  return cv.u;
}

// counted-vmcnt sync points (raw barrier: NO full drain, prefetch stays in flight)
#define SYNC_V4 do { __builtin_amdgcn_sched_barrier(0); \
  asm volatile("s_waitcnt vmcnt(4)" ::: "memory"); \
  __builtin_amdgcn_s_barrier(); \
  __builtin_amdgcn_sched_barrier(0); } while (0)
#define SYNC_V0 do { __builtin_amdgcn_sched_barrier(0); \
  asm volatile("s_waitcnt vmcnt(0)" ::: "memory"); \
  __builtin_amdgcn_s_barrier(); \
  __builtin_amdgcn_sched_barrier(0); } while (0)

// ---------------------------------------------------------------- kernel 1
__global__ __launch_bounds__(256) void wt_kernel(const float* __restrict__ wv,
                                                 const float* __restrict__ wk,
                                                 const float* __restrict__ wq,
                                                 f16* __restrict__ wt) {
  int idx = blockIdx.x * 256 + threadIdx.x;
  int p = idx >> 16;
  int rem = idx & 65535;
  int c = rem >> 8, k = rem & 255;
  const float* w = (p == 0) ? wv : (p == 1) ? wk : wq;
  wt[idx] = (f16)w[k * 256 + c];
}

// ---------------------------------------------------------------- kernel 2
// 512 threads, 8 waves: rg=wid&3 (16-row block), ch=wid>>2 (128-col half).
// dynamic LDS: xt 32K | ot 32K | wbuf 64K = 131072 B
__global__ __launch_bounds__(512, 1) void proj_kernel(const float* __restrict__ x,
                                                      uint8_t* __restrict__ ws) {
  extern __shared__ __align__(16) uint8_t plds[];
  uint8_t* xt = plds;
  uint8_t* ot = plds + 32768;
  uint8_t* wbuf = plds + 65536;

  const int tid = threadIdx.x;
  const int blk = blockIdx.x;
  const int lane = tid & 63, wid = tid >> 6;
  const int l15 = lane & 15, g = lane >> 4;
  const int rg = wid & 3, ch = wid >> 2;

  // ---- stage x tile (fp32 -> f16, row-swizzled) ----
  {
    int r = tid >> 3, c0 = (tid & 7) * 32;
    const float* src = x + (size_t)(blk * 64 + r) * 256 + c0;
    int sw = (r & 7) << 4;
#pragma unroll
    for (int j = 0; j < 4; ++j) {
      float4 f0 = *(const float4*)(src + j * 8);
      float4 f1 = *(const float4*)(src + j * 8 + 4);
      f16x8 h;
      h[0] = (f16)f0.x; h[1] = (f16)f0.y; h[2] = (f16)f0.z; h[3] = (f16)f0.w;
      h[4] = (f16)f1.x; h[5] = (f16)f1.y; h[6] = (f16)f1.z; h[7] = (f16)f1.w;
      *(f16x8*)(xt + r * 512 + ((c0 * 2 + j * 16) ^ sw)) = h;
    }
  }
  __syncthreads();

  const uint8_t* wtp = ws + WOFF;
  const int arow = rg * 16 + l15;
  const int asw = (arow & 7) << 4;

  for (int p = 0; p < 3; ++p) {
    f32x4 o[8];
#pragma unroll
    for (int t = 0; t < 8; ++t) o[t] = (f32x4){0.f, 0.f, 0.f, 0.f};

#pragma unroll
    for (int h = 0; h < 2; ++h) {
      __syncthreads();  // previous wbuf readers done
      // stage W^T[p][c 0..255][k h*128..+128] -> wbuf [c][256B], slot swz (c&7)<<4
      const uint8_t* wsrc = wtp + (size_t)p * 131072 + h * 256;
#pragma unroll
      for (int j = 0; j < 8; ++j) {
        int dst = j * 8192 + tid * 16;
        int c = dst >> 8, off = dst & 255;
        gll16(wsrc + c * 512 + (off ^ ((c & 7) << 4)), wbuf + j * 8192 + wid * 1024);
      }
      asm volatile("s_waitcnt vmcnt(0)" ::: "memory");
      __syncthreads();

#pragma unroll
      for (int kc2 = 0; kc2 < 4; ++kc2) {
        int kc = h * 4 + kc2;
        f16x8 a = *(const f16x8*)(xt + arow * 512 + ((kc * 64 + g * 16) ^ asw));
#pragma unroll
        for (int t = 0; t < 8; ++t) {
          int col = ch * 128 + t * 16 + l15;
          f16x8 b = *(const f16x8*)(wbuf + col * 256 +
                                    ((kc2 * 64 + g * 16) ^ ((col & 7) << 4)));
          o[t] = MFMA16(a, b, o[t]);
        }
      }
    }

    __syncthreads();
#pragma unroll
    for (int t = 0; t < 8; ++t) {
#pragma unroll
      for (int r = 0; r < 4; ++r) {
        int prow = rg * 16 + g * 4 + r;
        int pcol = ch * 128 + t * 16 + l15;
        int addr = prow * 512 + ((pcol * 2) ^ ((prow & 7) << 4));
        *(f16*)(ot + addr) = (f16)o[t][r];
      }
    }
    __syncthreads();

    if (p < 2) {
      uint8_t* dst = ws + (p == 0 ? VOFF : KOFF) + (size_t)blk * 32768;
#pragma unroll
      for (int jj = 0; jj < 4; ++jj) {
        u32x4 d = *(const u32x4*)(ot + jj * 8192 + tid * 16);
        *(u32x4*)(dst + jj * 8192 + tid * 16) = d;
      }
    } else {
      // qT: [c][128B] rows, 16B-slot swizzle (c&7)<<4
      int c = tid >> 1, half = tid & 1;
      int b2 = blk >> 6, kt2 = blk & 63;
      uint8_t* dst = ws + QOFF + (size_t)b2 * 2097152 + (size_t)kt2 * 32768 + c * 128;
#pragma unroll
      for (int jj2 = 0; jj2 < 4; ++jj2) {
        int jj = half * 4 + jj2;
        u32x4 d;
#pragma unroll
        for (int q = 0; q < 4; ++q) {
          int r0 = jj * 8 + q * 2, r1 = r0 + 1;
          uint32_t lo = *(const uint16_t*)(ot + r0 * 512 + ((c * 2) ^ ((r0 & 7) << 4)));
          uint32_t hi = *(const uint16_t*)(ot + r1 * 512 + ((c * 2) ^ ((r1 & 7) << 4)));
          d[q] = lo | (hi << 16);
        }
        *(u32x4*)(dst + ((jj * 16) ^ ((c & 7) << 4))) = d;
      }
    }
    __syncthreads();
  }
}

// ---------------------------------------------------------------- kernel 3
// 256 WGs x 512 thr. rg=wid&3 (rows rg*16..+16), kh=wid>>2 (keys kh*32..+32).
// LDS: K dbuf 2*32K @0 | Q dbuf 2*32K @65536 = 131072 B. P lives in registers.
// Schedule per tile: S1(vmcnt4,bar) [K(t) ready] -> issue K(t+1) -> QK ->
// softmax -> S2(vmcnt4,bar) [Q(t) ready] -> issue Q(t+1) -> PV.
__global__ __launch_bounds__(512, 2) void flash_kernel(const float* __restrict__ x,
                                                       const float* __restrict__ gptr,
                                                       float* __restrict__ out,
                                                       const uint8_t* __restrict__ ws) {
  extern __shared__ __align__(16) uint8_t lds[];
  const int tid = threadIdx.x, lane = tid & 63, wid = tid >> 6;
  const int l15 = lane & 15, g = lane >> 4;
  const int rg = wid & 3, kh = wid >> 2;

  int blk = blockIdx.x;
  int swz = (blk & 7) * 32 + (blk >> 3);
  int b = swz >> 6, rb = swz & 63;

  const uint8_t* ktile0 = ws + KOFF + (size_t)(b * 64) * 32768;
  const uint8_t* qtile0 = ws + QOFF + (size_t)b * 2097152;

  // V fragments first (their waitcnt mustn't drain the glls below)
  f16x8 vf[8];
  {
    int r = rg * 16 + l15;
    const uint8_t* vt = ws + VOFF + (size_t)(b * 64 + rb) * 32768 + r * 512;
    int sw = (r & 7) << 4;
#pragma unroll
    for (int cb = 0; cb < 8; ++cb)
      vf[cb] = *(const f16x8*)(vt + ((cb * 64 + g * 16) ^ sw));
  }
  const float gl2 = gptr[0] * 1.44269504088896f;

  // prologue: issue K(0) then Q(0)  (order matters: K older for vmcnt(4))
#pragma unroll
  for (int i = 0; i < 4; ++i)
    gll16(ktile0 + i * 8192 + tid * 16, lds + i * 8192 + wid * 1024);
#pragma unroll
  for (int i = 0; i < 4; ++i)
    gll16(qtile0 + i * 8192 + tid * 16, lds + 65536 + i * 8192 + wid * 1024);

  f32x4 o[16];
#pragma unroll
  for (int t = 0; t < 16; ++t) o[t] = (f32x4){0.f, 0.f, 0.f, 0.f};
  float m = -1e30f, l = 0.f;  // per-lane: row = l15 (uniform across g)

  const int rbase = (lane & 48) + ((lane & 48) >> 2);  // g*16 + g*4
  const int slo = ((lane >> 4) & 1) * 32 + (lane & 15);
  const int shi = slo + 16;
  const bool thi = (lane & 32) != 0;

  const int key0 = kh * 32 + l15;
  const int ksw = (l15 & 7) << 4;

  for (int kt = 0; kt < 64; ++kt) {
    const int cur = kt & 1;
    const uint8_t* kbuf = lds + cur * 32768;
    const uint8_t* qbuf = lds + 65536 + cur * 32768;

    SYNC_V4;  // S1: K(kt) resident (Q(kt) may still be in flight)

    if (kt < 63) {  // issue K(kt+1) into the other K buffer
      const uint8_t* kt1 = ktile0 + (size_t)(kt + 1) * 32768;
      uint8_t* nk = lds + (cur ^ 1) * 32768;
#pragma unroll
      for (int i = 0; i < 4; ++i)
        gll16(kt1 + i * 8192 + tid * 16, nk + i * 8192 + wid * 1024);
    }

    // ---- QK: batch-issue 16 ds_reads, then dense MFMA cluster ----
    f16x8 ka[16];
#pragma unroll
    for (int kc = 0; kc < 8; ++kc) {
      ka[kc * 2] = *(const f16x8*)(kbuf + key0 * 512 + ((kc * 64 + g * 16) ^ ksw));
      ka[kc * 2 + 1] =
          *(const f16x8*)(kbuf + (key0 + 16) * 512 + ((kc * 64 + g * 16) ^ ksw));
    }
    __builtin_amdgcn_sched_barrier(0);
    f32x4 s0 = (f32x4){0.f, 0.f, 0.f, 0.f};
    f32x4 s1 = (f32x4){0.f, 0.f, 0.f, 0.f};
    __builtin_amdgcn_s_setprio(1);
#pragma unroll
    for (int kc = 0; kc < 8; ++kc) {
      s0 = MFMA16(ka[kc * 2], vf[kc], s0);
      s1 = MFMA16(ka[kc * 2 + 1], vf[kc], s1);
    }
    __builtin_amdgcn_s_setprio(0);

    // ---- softmax: lane owns row l15; keys kh*32 + {t*16 + g*4 + r} ----
    float p[8];
#pragma unroll
    for (int r = 0; r < 4; ++r) {
      p[r] = s0[r] * gl2;
      p[4 + r] = s1[r] * gl2;
    }
    float rm = fmaxf(fmaxf(fmaxf(p[0], p[1]), fmaxf(p[2], p[3])),
                     fmaxf(fmaxf(p[4], p[5]), fmaxf(p[6], p[7])));
    rm = fmaxf(rm, __shfl_xor(rm, 16, 64));
    rm = fmaxf(rm, __shfl_xor(rm, 32, 64));

    if (!__all(rm <= m)) {  // exact defer-max
      float mn = fmaxf(m, rm);
      float sc = __builtin_amdgcn_exp2f(m - mn);
      m = mn;
      l *= sc;
      float sc0 = __shfl(sc, rbase + 0, 64);
      float sc1 = __shfl(sc, rbase + 1, 64);
      float sc2 = __shfl(sc, rbase + 2, 64);
      float sc3 = __shfl(sc, rbase + 3, 64);
#pragma unroll
      for (int t = 0; t < 16; ++t) {
        o[t][0] *= sc0; o[t][1] *= sc1; o[t][2] *= sc2; o[t][3] *= sc3;
      }
    }

    float rs = 0.f;
#pragma unroll
    for (int i = 0; i < 8; ++i) {
      p[i] = __builtin_amdgcn_exp2f(p[i] - m);
      rs += p[i];
    }
    rs += __shfl_xor(rs, 16, 64);
    rs += __shfl_xor(rs, 32, 64);
    l += rs;

    // build PV A-frag in-register
    uint32_t pk00 = pkf16(p[0], p[1]), pk01 = pkf16(p[2], p[3]);
    uint32_t pk10 = pkf16(p[4], p[5]), pk11 = pkf16(p[6], p[7]);
    uint32_t a0l = __shfl(pk00, slo, 64), a0h = __shfl(pk10, slo, 64);
    uint32_t a1l = __shfl(pk01, slo, 64), a1h = __shfl(pk11, slo, 64);
    uint32_t a2l = __shfl(pk00, shi, 64), a2h = __shfl(pk10, shi, 64);
    uint32_t a3l = __shfl(pk01, shi, 64), a3h = __shfl(pk11, shi, 64);
    union { uint32_t u[4]; f16x8 v; } pu;
    pu.u[0] = thi ? a0h : a0l;
    pu.u[1] = thi ? a1h : a1l;
    pu.u[2] = thi ? a2h : a2l;
    pu.u[3] = thi ? a3h : a3l;
    f16x8 pa = pu.v;

    // S2: Q(kt) resident (K(kt+1) stays in flight; last tile has none)
    if (kt < 63) { SYNC_V4; } else { SYNC_V0; }

    if (kt < 63) {  // issue Q(kt+1) into the other Q buffer
      const uint8_t* qt1 = qtile0 + (size_t)(kt + 1) * 32768;
      uint8_t* nq = lds + 65536 + (cur ^ 1) * 32768;
#pragma unroll
      for (int i = 0; i < 4; ++i)
        gll16(qt1 + i * 8192 + tid * 16, nq + i * 8192 + wid * 1024);
    }

    // ---- PV: batch-issue 16 qf reads, then dense MFMA cluster ----
    f16x8 qf[16];
#pragma unroll
    for (int t16 = 0; t16 < 16; ++t16) {
      int c = t16 * 16 + l15;
      qf[t16] = *(const f16x8*)(qbuf + c * 128 + ((kh * 64 + g * 16) ^ ((c & 7) << 4)));
    }
    __builtin_amdgcn_sched_barrier(0);
    __builtin_amdgcn_s_setprio(1);
#pragma unroll
    for (int t16 = 0; t16 < 16; ++t16) o[t16] = MFMA16(pa, qf[t16], o[t16]);
    __builtin_amdgcn_s_setprio(0);
  }

  __syncthreads();  // loop done (no glls outstanding); LDS free for merge

  // ---- merge kh=1 partials into kh=0, write out ----
  if (kh == 1) {
    uint8_t* ob = lds + rg * 16384;
#pragma unroll
    for (int t16 = 0; t16 < 16; ++t16) *(f32x4*)(ob + t16 * 1024 + lane * 16) = o[t16];
    if (g == 0) {
      uint8_t* mlb = lds + 65536 + rg * 128;
      *(float*)(mlb + l15 * 8) = m;
      *(float*)(mlb + l15 * 8 + 4) = l;
    }
  }
  __syncthreads();
  if (kh == 0) {
    const uint8_t* ob = lds + rg * 16384;
    const uint8_t* mlb = lds + 65536 + rg * 128;
    float pm = *(const float*)(mlb + l15 * 8);
    float pl = *(const float*)(mlb + l15 * 8 + 4);
    float mn = fmaxf(m, pm);
    float a = __builtin_amdgcn_exp2f(m - mn);
    float bs = __builtin_amdgcn_exp2f(pm - mn);
    float inv = 1.0f / (l * a + pl * bs);
    float ar[4], br[4], ir[4];
#pragma unroll
    for (int r = 0; r < 4; ++r) {
      ar[r] = __shfl(a, rbase + r, 64);
      br[r] = __shfl(bs, rbase + r, 64);
      ir[r] = __shfl(inv, rbase + r, 64);
    }
#pragma unroll
    for (int t16 = 0; t16 < 16; ++t16) {
      f32x4 po = *(const f32x4*)(ob + t16 * 1024 + lane * 16);
#pragma unroll
      for (int r = 0; r < 4; ++r) {
        size_t grow = (size_t)b * 4096 + (size_t)rb * 64 + rg * 16 + g * 4 + r;
        size_t idx = grow * 256 + t16 * 16 + l15;
        out[idx] = (o[t16][r] * ar[r] + po[r] * br[r]) * ir[r] + x[idx];
      }
    }
  }
}

// ---------------------------------------------------------------- launch
extern "C" void kernel_launch(void* const* d_in, const int* in_sizes, int n_in,
                              void* d_out, int out_size, void* d_ws, size_t ws_size,
                              hipStream_t stream) {
  (void)in_sizes; (void)n_in; (void)out_size; (void)ws_size;
  const float* x = (const float*)d_in[0];
  const float* wv = (const float*)d_in[1];
  const float* wk = (const float*)d_in[2];
  const float* wq = (const float*)d_in[3];
  const float* gamma = (const float*)d_in[4];
  float* out = (float*)d_out;
  uint8_t* ws = (uint8_t*)d_ws;

  wt_kernel<<<768, 256, 0, stream>>>(wv, wk, wq, (f16*)(ws + WOFF));

  (void)hipFuncSetAttribute((const void*)proj_kernel,
                            hipFuncAttributeMaxDynamicSharedMemorySize, 131072);
  proj_kernel<<<256, 512, 131072, stream>>>(x, ws);

  (void)hipFuncSetAttribute((const void*)flash_kernel,
                            hipFuncAttributeMaxDynamicSharedMemorySize, 131072);
  flash_kernel<<<256, 512, 131072, stream>>>(x, gamma, out, ws);
}